// Round 1
// baseline (182.371 us; speedup 1.0000x reference)
//
#include <hip/hip_runtime.h>

typedef _Float16 half8 __attribute__((ext_vector_type(8)));
typedef float f32x4 __attribute__((ext_vector_type(4)));

namespace {

constexpr int HEADS = 8;
constexpr int BATCH = 512;
constexpr int DH    = 1024;          // per-head dim
constexpr int CHW   = HEADS * DH;    // 8192

constexpr int BM = 128, BN = 128, BK = 32;
constexpr int LDW = BK + 8;          // padded LDS stride (halves): 40

__device__ __forceinline__ void cvt16(const float* f, half8& h0, half8& h1) {
#pragma unroll
  for (int i = 0; i < 8; ++i) { h0[i] = (_Float16)f[i]; h1[i] = (_Float16)f[8 + i]; }
}

// P[n,h,e] (or PT[h,e,n] if writeT) = sum_d X[n,h,d] * W[h,e,d] + bias[h,e]
__global__ __launch_bounds__(256) void proj_kernel(
    const float* __restrict__ X, const float* __restrict__ W,
    const float* __restrict__ bias, _Float16* __restrict__ P, int writeT) {
  __shared__ _Float16 As[BM * LDW];
  __shared__ _Float16 Bs[BN * LDW];
  const int tid = threadIdx.x;
  const int h  = blockIdx.y;
  const int tm = blockIdx.x & 3;   // 512/128
  const int tn = blockIdx.x >> 2;  // 1024/128
  const int lane = tid & 63, w = tid >> 6;
  const int wr = (w >> 1) * 64, wc = (w & 1) * 64;
  const int lr = lane & 15, lk = lane >> 4;

  const float* Ab = X + (size_t)tm * BM * CHW + (size_t)h * DH;
  const float* Bb = W + (size_t)h * DH * DH + (size_t)tn * BN * DH;
  const int srow = tid >> 1, sc0 = (tid & 1) * 16;

  f32x4 acc[4][4] = {};
#pragma unroll 1
  for (int kk = 0; kk < DH; kk += BK) {
    float fa[16], fb[16];
    const float* ga = Ab + (size_t)srow * CHW + kk + sc0;
    const float* gb = Bb + (size_t)srow * DH + kk + sc0;
#pragma unroll
    for (int i = 0; i < 4; ++i) {
      *(float4*)&fa[i * 4] = ((const float4*)ga)[i];
      *(float4*)&fb[i * 4] = ((const float4*)gb)[i];
    }
    __syncthreads();  // previous tile fully consumed
    half8 a0, a1, b0, b1;
    cvt16(fa, a0, a1);
    cvt16(fb, b0, b1);
    *(half8*)&As[srow * LDW + sc0]     = a0;
    *(half8*)&As[srow * LDW + sc0 + 8] = a1;
    *(half8*)&Bs[srow * LDW + sc0]     = b0;
    *(half8*)&Bs[srow * LDW + sc0 + 8] = b1;
    __syncthreads();  // tile ready
    half8 av[4], bv[4];
#pragma unroll
    for (int i = 0; i < 4; ++i)
      av[i] = *(const half8*)&As[(wr + i * 16 + lr) * LDW + lk * 8];
#pragma unroll
    for (int j = 0; j < 4; ++j)
      bv[j] = *(const half8*)&Bs[(wc + j * 16 + lr) * LDW + lk * 8];
#pragma unroll
    for (int i = 0; i < 4; ++i)
#pragma unroll
      for (int j = 0; j < 4; ++j)
        acc[i][j] = __builtin_amdgcn_mfma_f32_16x16x32_f16(av[i], bv[j], acc[i][j], 0, 0, 0);
  }

#pragma unroll
  for (int i = 0; i < 4; ++i)
#pragma unroll
    for (int j = 0; j < 4; ++j) {
      const int e = tn * BN + wc + j * 16 + lr;
      const float bb = bias[h * DH + e];
#pragma unroll
      for (int q = 0; q < 4; ++q) {
        const int n = tm * BM + wr + i * 16 + lk * 4 + q;
        const float val = acc[i][j][q] + bb;
        if (!writeT) P[((size_t)n * HEADS + h) * DH + e] = (_Float16)val;
        else         P[((size_t)h * DH + e) * BATCH + n] = (_Float16)val;
      }
    }
}

// S[h,n,m] = 32 * sum_e Qp[n,h,e] * Kp[m,h,e]   (fp32 out)
__global__ __launch_bounds__(256) void score_kernel(
    const _Float16* __restrict__ Qp, const _Float16* __restrict__ Kp,
    float* __restrict__ S) {
  __shared__ _Float16 As[BM * LDW];
  __shared__ _Float16 Bs[BN * LDW];
  const int tid = threadIdx.x;
  const int h  = blockIdx.y;
  const int tm = blockIdx.x & 3;   // n tiles
  const int tn = blockIdx.x >> 2;  // m tiles (0..3)
  const int lane = tid & 63, w = tid >> 6;
  const int wr = (w >> 1) * 64, wc = (w & 1) * 64;
  const int lr = lane & 15, lk = lane >> 4;

  const _Float16* Ab = Qp + ((size_t)tm * BM * HEADS + h) * DH;
  const _Float16* Bb = Kp + ((size_t)tn * BN * HEADS + h) * DH;
  const int srow = tid >> 1, sc0 = (tid & 1) * 16;

  f32x4 acc[4][4] = {};
#pragma unroll 1
  for (int kk = 0; kk < DH; kk += BK) {
    const _Float16* ga = Ab + (size_t)srow * CHW + kk + sc0;
    const _Float16* gb = Bb + (size_t)srow * CHW + kk + sc0;
    half8 a0 = ((const half8*)ga)[0], a1 = ((const half8*)ga)[1];
    half8 b0 = ((const half8*)gb)[0], b1 = ((const half8*)gb)[1];
    __syncthreads();
    *(half8*)&As[srow * LDW + sc0]     = a0;
    *(half8*)&As[srow * LDW + sc0 + 8] = a1;
    *(half8*)&Bs[srow * LDW + sc0]     = b0;
    *(half8*)&Bs[srow * LDW + sc0 + 8] = b1;
    __syncthreads();
    half8 av[4], bv[4];
#pragma unroll
    for (int i = 0; i < 4; ++i)
      av[i] = *(const half8*)&As[(wr + i * 16 + lr) * LDW + lk * 8];
#pragma unroll
    for (int j = 0; j < 4; ++j)
      bv[j] = *(const half8*)&Bs[(wc + j * 16 + lr) * LDW + lk * 8];
#pragma unroll
    for (int i = 0; i < 4; ++i)
#pragma unroll
      for (int j = 0; j < 4; ++j)
        acc[i][j] = __builtin_amdgcn_mfma_f32_16x16x32_f16(av[i], bv[j], acc[i][j], 0, 0, 0);
  }

#pragma unroll
  for (int i = 0; i < 4; ++i)
#pragma unroll
    for (int j = 0; j < 4; ++j) {
      const int m = tn * BN + wc + j * 16 + lr;
#pragma unroll
      for (int q = 0; q < 4; ++q) {
        const int n = tm * BM + wr + i * 16 + lk * 4 + q;
        S[((size_t)h * BATCH + n) * BATCH + m] = 32.0f * acc[i][j][q];
      }
    }
}

// row-softmax over m (512), one wave per (h,n) row; fp32 in, fp16 out
__global__ __launch_bounds__(64) void softmax_kernel(
    const float* __restrict__ S, _Float16* __restrict__ A) {
  const size_t r = (size_t)blockIdx.x * BATCH;
  const int l = threadIdx.x;
  float v[8];
  float mx = -1e30f;
#pragma unroll
  for (int i = 0; i < 8; ++i) { v[i] = S[r + i * 64 + l]; mx = fmaxf(mx, v[i]); }
#pragma unroll
  for (int off = 32; off; off >>= 1) mx = fmaxf(mx, __shfl_xor(mx, off));
  float sum = 0.f;
#pragma unroll
  for (int i = 0; i < 8; ++i) { v[i] = __expf(v[i] - mx); sum += v[i]; }
#pragma unroll
  for (int off = 32; off; off >>= 1) sum += __shfl_xor(sum, off);
  const float inv = 1.f / sum;
#pragma unroll
  for (int i = 0; i < 8; ++i) A[r + i * 64 + l] = (_Float16)(v[i] * inv);
}

// Out[n,h,e] = sum_m At[h,n,m] * VpT[h,e,m]   (fp32 out)
__global__ __launch_bounds__(256) void pv_kernel(
    const _Float16* __restrict__ At, const _Float16* __restrict__ VpT,
    float* __restrict__ Out) {
  __shared__ _Float16 As[BM * LDW];
  __shared__ _Float16 Bs[BN * LDW];
  const int tid = threadIdx.x;
  const int h  = blockIdx.y;
  const int tm = blockIdx.x & 3;   // n tiles
  const int tn = blockIdx.x >> 2;  // e tiles (0..7)
  const int lane = tid & 63, w = tid >> 6;
  const int wr = (w >> 1) * 64, wc = (w & 1) * 64;
  const int lr = lane & 15, lk = lane >> 4;

  const _Float16* Ab = At  + ((size_t)h * BATCH + tm * BM) * BATCH;
  const _Float16* Bb = VpT + ((size_t)h * DH   + tn * BN) * BATCH;
  const int srow = tid >> 1, sc0 = (tid & 1) * 16;

  f32x4 acc[4][4] = {};
#pragma unroll 1
  for (int kk = 0; kk < BATCH; kk += BK) {
    const _Float16* ga = Ab + (size_t)srow * BATCH + kk + sc0;
    const _Float16* gb = Bb + (size_t)srow * BATCH + kk + sc0;
    half8 a0 = ((const half8*)ga)[0], a1 = ((const half8*)ga)[1];
    half8 b0 = ((const half8*)gb)[0], b1 = ((const half8*)gb)[1];
    __syncthreads();
    *(half8*)&As[srow * LDW + sc0]     = a0;
    *(half8*)&As[srow * LDW + sc0 + 8] = a1;
    *(half8*)&Bs[srow * LDW + sc0]     = b0;
    *(half8*)&Bs[srow * LDW + sc0 + 8] = b1;
    __syncthreads();
    half8 av[4], bv[4];
#pragma unroll
    for (int i = 0; i < 4; ++i)
      av[i] = *(const half8*)&As[(wr + i * 16 + lr) * LDW + lk * 8];
#pragma unroll
    for (int j = 0; j < 4; ++j)
      bv[j] = *(const half8*)&Bs[(wc + j * 16 + lr) * LDW + lk * 8];
#pragma unroll
    for (int i = 0; i < 4; ++i)
#pragma unroll
      for (int j = 0; j < 4; ++j)
        acc[i][j] = __builtin_amdgcn_mfma_f32_16x16x32_f16(av[i], bv[j], acc[i][j], 0, 0, 0);
  }

#pragma unroll
  for (int i = 0; i < 4; ++i)
#pragma unroll
    for (int j = 0; j < 4; ++j) {
      const int e = tn * BN + wc + j * 16 + lr;
#pragma unroll
      for (int q = 0; q < 4; ++q) {
        const int n = tm * BM + wr + i * 16 + lk * 4 + q;
        Out[((size_t)n * HEADS + h) * DH + e] = acc[i][j][q];
      }
    }
}

}  // namespace

extern "C" void kernel_launch(void* const* d_in, const int* in_sizes, int n_in,
                              void* d_out, int out_size, void* d_ws, size_t ws_size,
                              hipStream_t stream) {
  (void)in_sizes; (void)n_in; (void)out_size; (void)ws_size;
  const float* q  = (const float*)d_in[0];
  const float* k  = (const float*)d_in[1];
  const float* v  = (const float*)d_in[2];
  const float* W1 = (const float*)d_in[3];
  const float* b1 = (const float*)d_in[4];
  const float* W2 = (const float*)d_in[5];
  const float* b2 = (const float*)d_in[6];
  const float* W3 = (const float*)d_in[7];
  const float* b3 = (const float*)d_in[8];
  float* out = (float*)d_out;

  // workspace layout (36 MB total)
  _Float16* Qp  = (_Float16*)d_ws;                       // 512*8*1024 halves = 8 MB
  _Float16* Kp  = Qp + (size_t)BATCH * HEADS * DH;       // 8 MB
  _Float16* VpT = Kp + (size_t)BATCH * HEADS * DH;       // 8 MB (stored [h][e][m])
  float*    S   = (float*)(VpT + (size_t)BATCH * HEADS * DH);  // 8*512*512 f32 = 8 MB
  _Float16* At  = (_Float16*)(S + (size_t)HEADS * BATCH * BATCH);  // 4 MB

  const dim3 blk(256);
  proj_kernel<<<dim3(32, 8), blk, 0, stream>>>(q, W1, b1, Qp, 0);
  proj_kernel<<<dim3(32, 8), blk, 0, stream>>>(k, W2, b2, Kp, 0);
  proj_kernel<<<dim3(32, 8), blk, 0, stream>>>(v, W3, b3, VpT, 1);
  score_kernel<<<dim3(16, 8), blk, 0, stream>>>(Qp, Kp, S);
  softmax_kernel<<<dim3(HEADS * BATCH), dim3(64), 0, stream>>>(S, At);
  pv_kernel<<<dim3(32, 8), blk, 0, stream>>>(At, VpT, out);
}

// Round 2
// 120.826 us; speedup vs baseline: 1.5094x; 1.5094x over previous
//
#include <hip/hip_runtime.h>

typedef _Float16 half8 __attribute__((ext_vector_type(8)));
typedef float f32x4 __attribute__((ext_vector_type(4)));

namespace {

constexpr int HEADS = 8;
constexpr int BATCH = 512;
constexpr int DH    = 1024;          // per-head dim
constexpr int CHW   = HEADS * DH;    // 8192

constexpr int BM = 128, BN = 128, BK = 32;
constexpr int LDW = BK + 8;          // padded LDS stride (halves): 40 -> 2-way-free banks

// dispatch-index d runs on XCD d%8; give each XCD a contiguous logical chunk
__device__ __forceinline__ int xcd_swz(int bid, int nwg) {
  const int q = nwg >> 3;  // all our grids are %8 == 0
  return (bid & 7) * q + (bid >> 3);
}

__device__ __forceinline__ void cvt16(const float* f, half8& h0, half8& h1) {
#pragma unroll
  for (int i = 0; i < 8; ++i) { h0[i] = (_Float16)f[i]; h1[i] = (_Float16)f[8 + i]; }
}

// Fused Q/K/V projection. z = l>>8 selects (X, W, bias, dst).
// P[n,h,e] = sum_d X[n,h,d]*W[h,e,d] + b[h,e]; V written transposed [h][e][n].
__global__ __launch_bounds__(256) void proj_kernel(
    const float* __restrict__ Xq, const float* __restrict__ Xk, const float* __restrict__ Xv,
    const float* __restrict__ W1, const float* __restrict__ b1,
    const float* __restrict__ W2, const float* __restrict__ b2,
    const float* __restrict__ W3, const float* __restrict__ b3,
    _Float16* __restrict__ Qp, _Float16* __restrict__ Kp, _Float16* __restrict__ VpT) {
  __shared__ _Float16 As[BM * LDW];
  __shared__ _Float16 Bs[BN * LDW];
  const int tid = threadIdx.x;
  const int l  = xcd_swz(blockIdx.x, 768);
  const int z  = l >> 8, rem = l & 255;
  const int h  = rem >> 5, bx = rem & 31;
  const int tm = bx & 3, tn = bx >> 2;
  const float* X    = (z == 0) ? Xq : (z == 1) ? Xk : Xv;
  const float* W    = (z == 0) ? W1 : (z == 1) ? W2 : W3;
  const float* bias = (z == 0) ? b1 : (z == 1) ? b2 : b3;
  _Float16*    P    = (z == 0) ? Qp : (z == 1) ? Kp : VpT;

  const int lane = tid & 63, w = tid >> 6;
  const int wr = (w >> 1) * 64, wc = (w & 1) * 64;
  const int lr = lane & 15, lk = lane >> 4;
  const int srow = tid >> 1, sc0 = (tid & 1) * 16;

  const float* ga = X + (size_t)(tm * BM + srow) * CHW + (size_t)h * DH + sc0;
  const float* gb = W + (size_t)h * DH * DH + (size_t)(tn * BN + srow) * DH + sc0;

  float4 ra[4], rb[4];
#pragma unroll
  for (int i = 0; i < 4; ++i) { ra[i] = ((const float4*)ga)[i]; rb[i] = ((const float4*)gb)[i]; }

  f32x4 acc[4][4] = {};
#pragma unroll 1
  for (int kk = 0; kk < DH; kk += BK) {
    half8 a0, a1, b0, b1;
    cvt16((const float*)ra, a0, a1);
    cvt16((const float*)rb, b0, b1);
    __syncthreads();  // previous tile fully consumed
    *(half8*)&As[srow * LDW + sc0]     = a0;
    *(half8*)&As[srow * LDW + sc0 + 8] = a1;
    *(half8*)&Bs[srow * LDW + sc0]     = b0;
    *(half8*)&Bs[srow * LDW + sc0 + 8] = b1;
    __syncthreads();  // tile ready
    if (kk + BK < DH) {  // prefetch next K-tile; latency hides under MFMA
      ga += BK; gb += BK;
#pragma unroll
      for (int i = 0; i < 4; ++i) { ra[i] = ((const float4*)ga)[i]; rb[i] = ((const float4*)gb)[i]; }
    }
    half8 av[4], bv[4];
#pragma unroll
    for (int i = 0; i < 4; ++i)
      av[i] = *(const half8*)&As[(wr + i * 16 + lr) * LDW + lk * 8];
#pragma unroll
    for (int j = 0; j < 4; ++j)
      bv[j] = *(const half8*)&Bs[(wc + j * 16 + lr) * LDW + lk * 8];
#pragma unroll
    for (int i = 0; i < 4; ++i)
#pragma unroll
      for (int j = 0; j < 4; ++j)
        acc[i][j] = __builtin_amdgcn_mfma_f32_16x16x32_f16(av[i], bv[j], acc[i][j], 0, 0, 0);
  }

#pragma unroll
  for (int i = 0; i < 4; ++i)
#pragma unroll
    for (int j = 0; j < 4; ++j) {
      const int e = tn * BN + wc + j * 16 + lr;
      const float bb = bias[h * DH + e];
#pragma unroll
      for (int q = 0; q < 4; ++q) {
        const int n = tm * BM + wr + i * 16 + lk * 4 + q;
        const float val = acc[i][j][q] + bb;
        if (z != 2) P[((size_t)n * HEADS + h) * DH + e] = (_Float16)val;
        else        P[((size_t)h * DH + e) * BATCH + n] = (_Float16)val;
      }
    }
}

// S[h,n,m] = 32 * sum_e Qp[n,h,e] * Kp[m,h,e]   (fp32 out)
__global__ __launch_bounds__(256) void score_kernel(
    const _Float16* __restrict__ Qp, const _Float16* __restrict__ Kp,
    float* __restrict__ S) {
  __shared__ _Float16 As[BM * LDW];
  __shared__ _Float16 Bs[BN * LDW];
  const int tid = threadIdx.x;
  const int l  = xcd_swz(blockIdx.x, 128);
  const int h  = l >> 4, bx = l & 15;
  const int tm = bx & 3, tn = bx >> 2;
  const int lane = tid & 63, w = tid >> 6;
  const int wr = (w >> 1) * 64, wc = (w & 1) * 64;
  const int lr = lane & 15, lk = lane >> 4;
  const int srow = tid >> 1, sc0 = (tid & 1) * 16;

  const _Float16* ga = Qp + ((size_t)(tm * BM + srow) * HEADS + h) * DH + sc0;
  const _Float16* gb = Kp + ((size_t)(tn * BN + srow) * HEADS + h) * DH + sc0;

  half8 ra0 = ((const half8*)ga)[0], ra1 = ((const half8*)ga)[1];
  half8 rb0 = ((const half8*)gb)[0], rb1 = ((const half8*)gb)[1];

  f32x4 acc[4][4] = {};
#pragma unroll 1
  for (int kk = 0; kk < DH; kk += BK) {
    __syncthreads();
    *(half8*)&As[srow * LDW + sc0]     = ra0;
    *(half8*)&As[srow * LDW + sc0 + 8] = ra1;
    *(half8*)&Bs[srow * LDW + sc0]     = rb0;
    *(half8*)&Bs[srow * LDW + sc0 + 8] = rb1;
    __syncthreads();
    if (kk + BK < DH) {
      ga += BK; gb += BK;
      ra0 = ((const half8*)ga)[0]; ra1 = ((const half8*)ga)[1];
      rb0 = ((const half8*)gb)[0]; rb1 = ((const half8*)gb)[1];
    }
    half8 av[4], bv[4];
#pragma unroll
    for (int i = 0; i < 4; ++i)
      av[i] = *(const half8*)&As[(wr + i * 16 + lr) * LDW + lk * 8];
#pragma unroll
    for (int j = 0; j < 4; ++j)
      bv[j] = *(const half8*)&Bs[(wc + j * 16 + lr) * LDW + lk * 8];
#pragma unroll
    for (int i = 0; i < 4; ++i)
#pragma unroll
      for (int j = 0; j < 4; ++j)
        acc[i][j] = __builtin_amdgcn_mfma_f32_16x16x32_f16(av[i], bv[j], acc[i][j], 0, 0, 0);
  }

#pragma unroll
  for (int i = 0; i < 4; ++i)
#pragma unroll
    for (int j = 0; j < 4; ++j) {
      const int m = tn * BN + wc + j * 16 + lr;
#pragma unroll
      for (int q = 0; q < 4; ++q) {
        const int n = tm * BM + wr + i * 16 + lk * 4 + q;
        S[((size_t)h * BATCH + n) * BATCH + m] = 32.0f * acc[i][j][q];
      }
    }
}

// row-softmax over m (512), one wave per (h,n) row; fp32 in, fp16 out
__global__ __launch_bounds__(64) void softmax_kernel(
    const float* __restrict__ S, _Float16* __restrict__ A) {
  const size_t r = (size_t)blockIdx.x * BATCH;
  const int l = threadIdx.x;
  float v[8];
  float mx = -1e30f;
#pragma unroll
  for (int i = 0; i < 8; ++i) { v[i] = S[r + i * 64 + l]; mx = fmaxf(mx, v[i]); }
#pragma unroll
  for (int off = 32; off; off >>= 1) mx = fmaxf(mx, __shfl_xor(mx, off));
  float sum = 0.f;
#pragma unroll
  for (int i = 0; i < 8; ++i) { v[i] = __expf(v[i] - mx); sum += v[i]; }
#pragma unroll
  for (int off = 32; off; off >>= 1) sum += __shfl_xor(sum, off);
  const float inv = 1.f / sum;
#pragma unroll
  for (int i = 0; i < 8; ++i) A[r + i * 64 + l] = (_Float16)(v[i] * inv);
}

// Out[n,h,e] = sum_m At[h,n,m] * VpT[h,e,m]   (fp32 out)
__global__ __launch_bounds__(256) void pv_kernel(
    const _Float16* __restrict__ At, const _Float16* __restrict__ VpT,
    float* __restrict__ Out) {
  __shared__ _Float16 As[BM * LDW];
  __shared__ _Float16 Bs[BN * LDW];
  const int tid = threadIdx.x;
  const int l  = xcd_swz(blockIdx.x, 256);
  const int h  = l >> 5, bx = l & 31;
  const int tm = bx & 3, tn = bx >> 2;
  const int lane = tid & 63, w = tid >> 6;
  const int wr = (w >> 1) * 64, wc = (w & 1) * 64;
  const int lr = lane & 15, lk = lane >> 4;
  const int srow = tid >> 1, sc0 = (tid & 1) * 16;

  const _Float16* ga = At  + ((size_t)h * BATCH + tm * BM + srow) * BATCH + sc0;
  const _Float16* gb = VpT + ((size_t)h * DH   + tn * BN + srow) * BATCH + sc0;

  half8 ra0 = ((const half8*)ga)[0], ra1 = ((const half8*)ga)[1];
  half8 rb0 = ((const half8*)gb)[0], rb1 = ((const half8*)gb)[1];

  f32x4 acc[4][4] = {};
#pragma unroll 1
  for (int kk = 0; kk < BATCH; kk += BK) {
    __syncthreads();
    *(half8*)&As[srow * LDW + sc0]     = ra0;
    *(half8*)&As[srow * LDW + sc0 + 8] = ra1;
    *(half8*)&Bs[srow * LDW + sc0]     = rb0;
    *(half8*)&Bs[srow * LDW + sc0 + 8] = rb1;
    __syncthreads();
    if (kk + BK < BATCH) {
      ga += BK; gb += BK;
      ra0 = ((const half8*)ga)[0]; ra1 = ((const half8*)ga)[1];
      rb0 = ((const half8*)gb)[0]; rb1 = ((const half8*)gb)[1];
    }
    half8 av[4], bv[4];
#pragma unroll
    for (int i = 0; i < 4; ++i)
      av[i] = *(const half8*)&As[(wr + i * 16 + lr) * LDW + lk * 8];
#pragma unroll
    for (int j = 0; j < 4; ++j)
      bv[j] = *(const half8*)&Bs[(wc + j * 16 + lr) * LDW + lk * 8];
#pragma unroll
    for (int i = 0; i < 4; ++i)
#pragma unroll
      for (int j = 0; j < 4; ++j)
        acc[i][j] = __builtin_amdgcn_mfma_f32_16x16x32_f16(av[i], bv[j], acc[i][j], 0, 0, 0);
  }

#pragma unroll
  for (int i = 0; i < 4; ++i)
#pragma unroll
    for (int j = 0; j < 4; ++j) {
      const int e = tn * BN + wc + j * 16 + lr;
#pragma unroll
      for (int q = 0; q < 4; ++q) {
        const int n = tm * BM + wr + i * 16 + lk * 4 + q;
        Out[((size_t)n * HEADS + h) * DH + e] = acc[i][j][q];
      }
    }
}

}  // namespace

extern "C" void kernel_launch(void* const* d_in, const int* in_sizes, int n_in,
                              void* d_out, int out_size, void* d_ws, size_t ws_size,
                              hipStream_t stream) {
  (void)in_sizes; (void)n_in; (void)out_size; (void)ws_size;
  const float* q  = (const float*)d_in[0];
  const float* k  = (const float*)d_in[1];
  const float* v  = (const float*)d_in[2];
  const float* W1 = (const float*)d_in[3];
  const float* b1 = (const float*)d_in[4];
  const float* W2 = (const float*)d_in[5];
  const float* b2 = (const float*)d_in[6];
  const float* W3 = (const float*)d_in[7];
  const float* b3 = (const float*)d_in[8];
  float* out = (float*)d_out;

  // workspace layout (36 MB total)
  _Float16* Qp  = (_Float16*)d_ws;                       // 8 MB
  _Float16* Kp  = Qp + (size_t)BATCH * HEADS * DH;       // 8 MB
  _Float16* VpT = Kp + (size_t)BATCH * HEADS * DH;       // 8 MB ([h][e][m])
  float*    S   = (float*)(VpT + (size_t)BATCH * HEADS * DH);      // 8 MB
  _Float16* At  = (_Float16*)(S + (size_t)HEADS * BATCH * BATCH);  // 4 MB

  const dim3 blk(256);
  proj_kernel<<<dim3(768), blk, 0, stream>>>(q, k, v, W1, b1, W2, b2, W3, b3, Qp, Kp, VpT);
  score_kernel<<<dim3(128), blk, 0, stream>>>(Qp, Kp, S);
  softmax_kernel<<<dim3(HEADS * BATCH), dim3(64), 0, stream>>>(S, At);
  pv_kernel<<<dim3(256), blk, 0, stream>>>(At, VpT, out);
}